// Round 3
// baseline (225.708 us; speedup 1.0000x reference)
//
#include <hip/hip_runtime.h>
#include <stdint.h>

typedef __attribute__((ext_vector_type(8))) short short8;
typedef __attribute__((ext_vector_type(4))) float floatx4;
typedef __attribute__((ext_vector_type(16))) float floatx16;
typedef __attribute__((ext_vector_type(2))) unsigned int uintx2;
typedef unsigned short u16;
typedef unsigned int u32;

#define EDIM 128
#define FDIM 512
#define BM 64
#define FC 128            // F chunk; 4 chunks; h double-buffered in LDS
#define QSTR (EDIM + 8)   // 136 bf16 = 272 B row stride (16B aligned)
#define HSTR (FC + 8)     // 136 bf16

// round-to-nearest-even float -> bf16
__device__ __forceinline__ u32 f2bf_rne(float f) {
    u32 u = __builtin_bit_cast(u32, f);
    return (u + 0x7fffu + ((u >> 16) & 1u)) >> 16;
}
__device__ __forceinline__ u32 pk2bf(float lo, float hi) {
    return f2bf_rne(lo) | (f2bf_rne(hi) << 16);
}

// Convert W1 (512x128 f32) and W2 (128x512 f32) to bf16 into workspace.
__global__ __launch_bounds__(256) void ffq_prep(const float* __restrict__ W1,
                                                const float* __restrict__ W2,
                                                u16* __restrict__ wb) {
    int i4 = blockIdx.x * 256 + threadIdx.x;  // float4 index, 0..32767
    const float4* src = (i4 < 16384)
        ? (reinterpret_cast<const float4*>(W1) + i4)
        : (reinterpret_cast<const float4*>(W2) + (i4 - 16384));
    float4 v = *src;
    uintx2 p;
    p.x = pk2bf(v.x, v.y);
    p.y = pk2bf(v.z, v.w);
    *(reinterpret_cast<uintx2*>(wb) + i4) = p;
}

// Fused q = cos(x)*cos(theta); h = relu(q@W1^T); out = h@W2^T.
// 64 rows/block, 8 waves, MFMA 32x32x16 bf16.
// Wave = (mg = wv&1: 32 m-rows, gg = wv>>1: 32 f-cols per chunk / 32 e-cols).
// Per GEMM per chunk: 8 ds_read_b128 + 8 global b128 + 8 MFMA (1:1:1 —
// LDS reads per block halved vs 16x16 layout; MFMA-pipe cycles -17%).
__global__ __launch_bounds__(512, 6) void ffq_main(const float* __restrict__ x,
                                                   const float* __restrict__ theta,
                                                   const u16* __restrict__ wb,
                                                   float* __restrict__ out) {
    __shared__ u16 qs[BM * QSTR];       // 17408 B
    __shared__ u16 hs[2][BM * HSTR];    // 34816 B (total 52224 B -> 3 blocks/CU)

    const int t = threadIdx.x;
    const int lane = t & 63;
    const int wv = t >> 6;        // wave id 0..7
    const int l31 = lane & 31;
    const int h5 = lane >> 5;     // half-wave 0/1
    const int mg = wv & 1;        // m-group: rows mg*32..mg*32+31
    const int gg = wv >> 1;       // f-group (GEMM1) / e-group (GEMM2): 0..3

    // ---- stage q = cos(x)*cos(theta) into LDS (bf16) ----
    {
        const float4* xin = reinterpret_cast<const float4*>(x) +
                            (size_t)blockIdx.x * (BM * EDIM / 4);
        const int et = (t & 31) * 4;  // e offset; same each r since 512 % 32 == 0
        float c0 = __cosf(theta[et + 0]);
        float c1 = __cosf(theta[et + 1]);
        float c2 = __cosf(theta[et + 2]);
        float c3 = __cosf(theta[et + 3]);
        #pragma unroll
        for (int r = 0; r < 4; ++r) {
            int i = t + 512 * r;   // float4 index within tile
            int m = i >> 5;        // row 0..63
            float4 v = xin[i];
            uintx2 p;
            p.x = pk2bf(__cosf(v.x) * c0, __cosf(v.y) * c1);
            p.y = pk2bf(__cosf(v.z) * c2, __cosf(v.w) * c3);
            *reinterpret_cast<uintx2*>(&qs[m * QSTR + et]) = p;
        }
    }
    __syncthreads();

    const u16* W1b = wb;                  // [512][128] bf16
    const u16* W2b = wb + FDIM * EDIM;    // [128][512] bf16

    floatx16 acc2 = {0.f,0.f,0.f,0.f,0.f,0.f,0.f,0.f,
                     0.f,0.f,0.f,0.f,0.f,0.f,0.f,0.f};  // out^T 32x32 tile

    const u16* qp = &qs[(mg * 32 + l31) * QSTR + h5 * 8];  // B-frag base (q)
    const u16* hp0 = &hs[0][(mg * 32 + l31) * HSTR + h5 * 8];
    const u16* hp1 = &hs[1][(mg * 32 + l31) * HSTR + h5 * 8];

    #pragma unroll
    for (int c = 0; c < 4; ++c) {
        u16* hb = hs[c & 1];

        // ---- GEMM1: h^T 32x32 tile = W1[f0..f0+31] x q^T, K = 128 ----
        floatx16 acc1 = {0.f,0.f,0.f,0.f,0.f,0.f,0.f,0.f,
                         0.f,0.f,0.f,0.f,0.f,0.f,0.f,0.f};
        const u16* w1p = W1b + (size_t)(c * FC + gg * 32 + l31) * EDIM + h5 * 8;
        #pragma unroll
        for (int k = 0; k < 8; ++k) {   // K = 128 = 8 x 16
            short8 a = *reinterpret_cast<const short8*>(w1p + k * 16);
            short8 b = *reinterpret_cast<const short8*>(qp + k * 16);
            acc1 = __builtin_amdgcn_mfma_f32_32x32x16_bf16(a, b, acc1, 0, 0, 0);
        }

        // relu + bf16(RNE) -> h buffer. D: col m=l31, row f=(reg&3)+8*(reg>>2)+4*h5
        const int hrow = (mg * 32 + l31) * HSTR;
        #pragma unroll
        for (int rq = 0; rq < 4; ++rq) {
            const int fl = gg * 32 + rq * 8 + h5 * 4;
            uintx2 p;
            p.x = pk2bf(fmaxf(acc1[rq * 4 + 0], 0.f), fmaxf(acc1[rq * 4 + 1], 0.f));
            p.y = pk2bf(fmaxf(acc1[rq * 4 + 2], 0.f), fmaxf(acc1[rq * 4 + 3], 0.f));
            *reinterpret_cast<uintx2*>(&hb[hrow + fl]) = p;
        }
        __syncthreads();   // the only barrier this chunk

        // ---- GEMM2: out^T 32x32 tile += W2[e0..e0+31] x h^T, chunk K = 128 ----
        const u16* w2p = W2b + (size_t)(gg * 32 + l31) * FDIM + c * FC + h5 * 8;
        const u16* hp = (c & 1) ? hp1 : hp0;
        #pragma unroll
        for (int k = 0; k < 8; ++k) {
            short8 a = *reinterpret_cast<const short8*>(w2p + k * 16);
            short8 b = *reinterpret_cast<const short8*>(hp + k * 16);
            acc2 = __builtin_amdgcn_mfma_f32_32x32x16_bf16(a, b, acc2, 0, 0, 0);
        }
    }

    // ---- epilogue: D col m=l31, row e=gg*32+(reg&3)+8*(reg>>2)+4*h5 ----
    float* op = out + (size_t)blockIdx.x * BM * EDIM +
                (mg * 32 + l31) * EDIM + gg * 32 + h5 * 4;
    #pragma unroll
    for (int rq = 0; rq < 4; ++rq) {
        floatx4 v;
        v[0] = acc2[rq * 4 + 0];
        v[1] = acc2[rq * 4 + 1];
        v[2] = acc2[rq * 4 + 2];
        v[3] = acc2[rq * 4 + 3];
        *reinterpret_cast<floatx4*>(op + rq * 8) = v;
    }
}

extern "C" void kernel_launch(void* const* d_in, const int* in_sizes, int n_in,
                              void* d_out, int out_size, void* d_ws, size_t ws_size,
                              hipStream_t stream) {
    const float* x     = (const float*)d_in[0];  // [32,4096,128]
    const float* theta = (const float*)d_in[1];  // [128]
    const float* W1    = (const float*)d_in[2];  // [512,128]
    const float* W2    = (const float*)d_in[3];  // [128,512]
    u16* wb    = (u16*)d_ws;                     // 256 KB bf16 weights
    float* out = (float*)d_out;                  // [32,4096,128]

    ffq_prep<<<128, 256, 0, stream>>>(W1, W2, wb);
    ffq_main<<<2048, 512, 0, stream>>>(x, theta, wb, out);
}

// Round 4
// 150.640 us; speedup vs baseline: 1.4983x; 1.4983x over previous
//
#include <hip/hip_runtime.h>
#include <stdint.h>

typedef __attribute__((ext_vector_type(8))) short short8;
typedef __attribute__((ext_vector_type(4))) float floatx4;
typedef __attribute__((ext_vector_type(16))) float floatx16;
typedef __attribute__((ext_vector_type(2))) unsigned int uintx2;
typedef unsigned short u16;
typedef unsigned int u32;

#define EDIM 128
#define FDIM 512
#define BM 64
#define FC 128            // F chunk; 4 chunks; h double-buffered in LDS
#define QSTR (EDIM + 8)   // 136 bf16 = 272 B row stride (16B aligned)
#define HSTR (FC + 8)     // 136 bf16

// round-to-nearest-even float -> bf16
__device__ __forceinline__ u32 f2bf_rne(float f) {
    u32 u = __builtin_bit_cast(u32, f);
    return (u + 0x7fffu + ((u >> 16) & 1u)) >> 16;
}
__device__ __forceinline__ u32 pk2bf(float lo, float hi) {
    return f2bf_rne(lo) | (f2bf_rne(hi) << 16);
}

// Pre-swizzle W1/W2 to bf16 in MFMA A-fragment lane order so the main
// kernel's A-loads are base + k*1024B + lane*16B (fully coalesced, hoistable).
//   W1s group index g  = tile(c*4+gg)*512 + k*64 + lane   (16B per group)
//        holds W1[tile*32 + (lane&31)][k*16 + (lane>>5)*8 + j], j=0..7
//   W2s group index g2 = tile(gg*4+c)*512 + k*64 + lane
//        holds W2[gg*32 + (lane&31)][c*128 + k*16 + (lane>>5)*8 + j]
__global__ __launch_bounds__(256) void ffq_prep(const float* __restrict__ W1,
                                                const float* __restrict__ W2,
                                                u16* __restrict__ wb) {
    int g = blockIdx.x * 256 + threadIdx.x;   // 0..16383
    int lane = g & 63;
    int kk = (g >> 6) & 7;
    int idx = (g >> 9) & 15;
    int l31 = lane & 31, h5 = lane >> 5;
    const float* src;
    if (g < 8192) {
        src = W1 + (idx * 32 + l31) * EDIM + kk * 16 + h5 * 8;
    } else {
        int gg = idx >> 2, c = idx & 3;
        src = W2 + (gg * 32 + l31) * FDIM + c * 128 + kk * 16 + h5 * 8;
    }
    float4 v0 = *reinterpret_cast<const float4*>(src);
    float4 v1 = *reinterpret_cast<const float4*>(src + 4);
    uint4 p;
    p.x = pk2bf(v0.x, v0.y);
    p.y = pk2bf(v0.z, v0.w);
    p.z = pk2bf(v1.x, v1.y);
    p.w = pk2bf(v1.z, v1.w);
    reinterpret_cast<uint4*>(wb)[g] = p;
}

// Fused q = cos(x)*cos(theta); h = relu(q@W1^T); out = h@W2^T.
// 64 rows/block, 8 waves, MFMA 32x32x16 bf16.
// Wave = (mg = wv&1: 32 m-rows, gg = wv>>1: 32 f-cols per chunk / 32 e-cols).
__global__ __launch_bounds__(512, 6) void ffq_main(const float* __restrict__ x,
                                                   const float* __restrict__ theta,
                                                   const u16* __restrict__ wb,
                                                   float* __restrict__ out) {
    __shared__ u16 qs[BM * QSTR];       // 17408 B
    __shared__ u16 hs[2][BM * HSTR];    // 34816 B (total 52224 B -> 3 blocks/CU)

    const int t = threadIdx.x;
    const int lane = t & 63;
    const int wv = t >> 6;        // wave id 0..7
    const int l31 = lane & 31;
    const int h5 = lane >> 5;     // half-wave 0/1
    const int mg = wv & 1;        // m-group: rows mg*32..mg*32+31
    const int gg = wv >> 1;       // f-group (GEMM1) / e-group (GEMM2): 0..3

    // ---- stage q = cos(x)*cos(theta) into LDS (bf16) ----
    {
        const float4* xin = reinterpret_cast<const float4*>(x) +
                            (size_t)blockIdx.x * (BM * EDIM / 4);
        const int et = (t & 31) * 4;  // e offset; same each r since 512 % 32 == 0
        float c0 = __cosf(theta[et + 0]);
        float c1 = __cosf(theta[et + 1]);
        float c2 = __cosf(theta[et + 2]);
        float c3 = __cosf(theta[et + 3]);
        #pragma unroll
        for (int r = 0; r < 4; ++r) {
            int i = t + 512 * r;   // float4 index within tile
            int m = i >> 5;        // row 0..63
            float4 v = xin[i];
            uintx2 p;
            p.x = pk2bf(__cosf(v.x) * c0, __cosf(v.y) * c1);
            p.y = pk2bf(__cosf(v.z) * c2, __cosf(v.w) * c3);
            *reinterpret_cast<uintx2*>(&qs[m * QSTR + et]) = p;
        }
    }
    __syncthreads();

    const u16* W1s = wb;                  // swizzled, see ffq_prep
    const u16* W2s = wb + FDIM * EDIM;    // swizzled

    floatx16 acc2 = {0.f,0.f,0.f,0.f,0.f,0.f,0.f,0.f,
                     0.f,0.f,0.f,0.f,0.f,0.f,0.f,0.f};  // out^T 32x32 tile

    const u16* qp  = &qs[(mg * 32 + l31) * QSTR + h5 * 8];  // B-frag base (q)
    const u16* hp0 = &hs[0][(mg * 32 + l31) * HSTR + h5 * 8];
    const u16* hp1 = &hs[1][(mg * 32 + l31) * HSTR + h5 * 8];

    #pragma unroll
    for (int c = 0; c < 4; ++c) {
        u16* hb = hs[c & 1];

        // ---- GEMM1: h^T 32x32 tile = W1_tile x q^T, K = 128 ----
        floatx16 acc1 = {0.f,0.f,0.f,0.f,0.f,0.f,0.f,0.f,
                         0.f,0.f,0.f,0.f,0.f,0.f,0.f,0.f};
        const u16* w1p = W1s + (size_t)(c * 4 + gg) * 4096 + lane * 8;
        #pragma unroll
        for (int k = 0; k < 8; ++k) {   // K = 128 = 8 x 16
            short8 a = *reinterpret_cast<const short8*>(w1p + k * 512);
            short8 b = *reinterpret_cast<const short8*>(qp + k * 16);
            acc1 = __builtin_amdgcn_mfma_f32_32x32x16_bf16(a, b, acc1, 0, 0, 0);
        }

        // relu + bf16(RNE) -> h buffer. D: col m=l31, row f=(reg&3)+8*(reg>>2)+4*h5
        const int hrow = (mg * 32 + l31) * HSTR;
        #pragma unroll
        for (int rq = 0; rq < 4; ++rq) {
            const int fl = gg * 32 + rq * 8 + h5 * 4;
            uintx2 p;
            p.x = pk2bf(fmaxf(acc1[rq * 4 + 0], 0.f), fmaxf(acc1[rq * 4 + 1], 0.f));
            p.y = pk2bf(fmaxf(acc1[rq * 4 + 2], 0.f), fmaxf(acc1[rq * 4 + 3], 0.f));
            *reinterpret_cast<uintx2*>(&hb[hrow + fl]) = p;
        }
        __syncthreads();   // the only barrier this chunk

        // ---- GEMM2: out^T 32x32 tile += W2_tile x h^T, chunk K = 128 ----
        const u16* w2p = W2s + (size_t)(gg * 4 + c) * 4096 + lane * 8;
        const u16* hp = (c & 1) ? hp1 : hp0;
        #pragma unroll
        for (int k = 0; k < 8; ++k) {
            short8 a = *reinterpret_cast<const short8*>(w2p + k * 512);
            short8 b = *reinterpret_cast<const short8*>(hp + k * 16);
            acc2 = __builtin_amdgcn_mfma_f32_32x32x16_bf16(a, b, acc2, 0, 0, 0);
        }
    }

    // ---- epilogue: D col m=l31, row e=gg*32+(reg&3)+8*(reg>>2)+4*h5 ----
    float* op = out + (size_t)blockIdx.x * BM * EDIM +
                (mg * 32 + l31) * EDIM + gg * 32 + h5 * 4;
    #pragma unroll
    for (int rq = 0; rq < 4; ++rq) {
        floatx4 v;
        v[0] = acc2[rq * 4 + 0];
        v[1] = acc2[rq * 4 + 1];
        v[2] = acc2[rq * 4 + 2];
        v[3] = acc2[rq * 4 + 3];
        *reinterpret_cast<floatx4*>(op + rq * 8) = v;
    }
}

extern "C" void kernel_launch(void* const* d_in, const int* in_sizes, int n_in,
                              void* d_out, int out_size, void* d_ws, size_t ws_size,
                              hipStream_t stream) {
    const float* x     = (const float*)d_in[0];  // [32,4096,128]
    const float* theta = (const float*)d_in[1];  // [128]
    const float* W1    = (const float*)d_in[2];  // [512,128]
    const float* W2    = (const float*)d_in[3];  // [128,512]
    u16* wb    = (u16*)d_ws;                     // 256 KB bf16 weights (swizzled)
    float* out = (float*)d_out;                  // [32,4096,128]

    ffq_prep<<<64, 256, 0, stream>>>(W1, W2, wb);
    ffq_main<<<2048, 512, 0, stream>>>(x, theta, wb, out);
}